// Round 1
// baseline (1664.721 us; speedup 1.0000x reference)
//
#include <hip/hip_runtime.h>

// 2D Haar DWT: x (8,128,512,512) f32 -> 4 bands (8,128,256,256) f32 each,
// concatenated in d_out in order (hh, hl, lh, ll).
//
// hh = 0.5*(a - b - c + d)   a = x[2i,2j]   b = x[2i,2j+1]
// hl = 0.5*(a + b - c - d)   c = x[2i+1,2j] d = x[2i+1,2j+1]
// lh = 0.5*(a - b + c - d)
// ll = 0.5*(a + b + c + d)

#define IW 512
#define IH 512
#define NC 1024              // 8*128 fused batch*channel
#define OW 256
#define OH 256
#define BAND ((size_t)NC * OH * OW)   // 67,108,864 elements per band

__global__ __launch_bounds__(256) void dwt_haar_kernel(
    const float* __restrict__ x, float* __restrict__ out)
{
    const unsigned tid = blockIdx.x * blockDim.x + threadIdx.x;
    const unsigned jt = tid & 63u;           // quad-of-4-outputs index along row (64 per row)
    const unsigned r  = (tid >> 6) & 255u;   // output row
    const unsigned nc = tid >> 14;           // fused batch*channel

    const size_t in_off = (size_t)nc * (IW * IH) + (size_t)(2u * r) * IW + 8u * jt;
    const float4 v0 = *(const float4*)(x + in_off);           // row 2r, cols 8jt..8jt+3
    const float4 v1 = *(const float4*)(x + in_off + 4);       // row 2r, cols 8jt+4..8jt+7
    const float4 v2 = *(const float4*)(x + in_off + IW);      // row 2r+1
    const float4 v3 = *(const float4*)(x + in_off + IW + 4);

    float4 hh, hl, lh, ll;
    // For output element k: a=even col (row 2r), b=odd col (row 2r),
    //                       c=even col (row 2r+1), d=odd col (row 2r+1)
#define DWT_COMP(comp, A, B, C, D)          \
    hh.comp = 0.5f * ((A) - (B) - (C) + (D)); \
    hl.comp = 0.5f * ((A) + (B) - (C) - (D)); \
    lh.comp = 0.5f * ((A) - (B) + (C) - (D)); \
    ll.comp = 0.5f * ((A) + (B) + (C) + (D));

    DWT_COMP(x, v0.x, v0.y, v2.x, v2.y)
    DWT_COMP(y, v0.z, v0.w, v2.z, v2.w)
    DWT_COMP(z, v1.x, v1.y, v3.x, v3.y)
    DWT_COMP(w, v1.z, v1.w, v3.z, v3.w)
#undef DWT_COMP

    const size_t out_off = (size_t)nc * (OH * OW) + (size_t)r * OW + 4u * jt;
    *(float4*)(out + out_off)            = hh;
    *(float4*)(out + BAND + out_off)     = hl;
    *(float4*)(out + 2 * BAND + out_off) = lh;
    *(float4*)(out + 3 * BAND + out_off) = ll;
}

extern "C" void kernel_launch(void* const* d_in, const int* in_sizes, int n_in,
                              void* d_out, int out_size, void* d_ws, size_t ws_size,
                              hipStream_t stream)
{
    const float* x = (const float*)d_in[0];
    float* out = (float*)d_out;
    // total threads = NC * OH * 64 = 16,777,216 -> 65,536 blocks of 256
    const unsigned total_threads = NC * OH * 64;
    dim3 grid(total_threads / 256), block(256);
    dwt_haar_kernel<<<grid, block, 0, stream>>>(x, out);
}